// Round 1
// baseline (126.798 us; speedup 1.0000x reference)
//
#include <hip/hip_runtime.h>
#include <math.h>

#define N_NODES 65536
#define G_SEG   512
#define T_ELEMS (300 * 2048)   // T2[zm][j][m]: 300 x 64 x 32 floats = 2.4 MB

// ---------------------------------------------------------------------------
// Kernel A: T2[zm][j][m] = (1/sqrt(2048)) * sum_u feat_zm[u] * W2[m][l*1024+u*16+wi]
//   zm = z*3 + mol, j = l*16 + wi.  Folds W2/sqrt(32) and the einsum /sqrt(64).
// grid (300, 4): blockIdx.x = zm, blockIdx.y = l. 256 threads = 16 wi x 16 m_lo.
// ---------------------------------------------------------------------------
__global__ __launch_bounds__(256) void build_T(
    const float* __restrict__ emb_z, const float* __restrict__ emb_mol,
    const float* __restrict__ W2, float* __restrict__ T2)
{
    __shared__ float feat[64];
    const int zm = blockIdx.x;
    const int l  = blockIdx.y;
    const int z  = zm / 3, mo = zm % 3;
    const int t  = threadIdx.x;
    if (t < 48)      feat[t] = emb_z[z * 48 + t];
    else if (t < 64) feat[t] = emb_mol[mo * 16 + (t - 48)];
    __syncthreads();

    const float scale = 0.02209708691207961f;  // 1/sqrt(2048)
    const int wi  = t & 15;
    const int mlo = t >> 4;   // 0..15
#pragma unroll
    for (int i = 0; i < 2; ++i) {
        const int m = mlo + 16 * i;
        const float* w2p = W2 + m * 4096 + l * 1024 + wi;  // stride 16 over u
        float acc = 0.f;
#pragma unroll 8
        for (int u = 0; u < 64; ++u)
            acc = fmaf(feat[u], w2p[u * 16], acc);
        const int j = l * 16 + wi;
        T2[zm * 2048 + j * 32 + m] = acc * scale;
    }
}

// ---------------------------------------------------------------------------
// Kernel B: per-node pipeline + register-accumulated segment sum.
// One wave handles nPerWave contiguous nodes. Lane j = l*16+wi owns xw[l][wi];
// it keeps (2l+1) running accumulators (value = xw * sh_l[k]) and flushes with
// atomics only when the (sorted) batch id changes.
// ---------------------------------------------------------------------------
__global__ __launch_bounds__(256) void node_kernel(
    const float* __restrict__ pos, const int* __restrict__ xz,
    const int* __restrict__ mol, const int* __restrict__ batch,
    const float* __restrict__ W1, const float* __restrict__ T2,
    float* __restrict__ sums, float* __restrict__ counts,
    float silu_c, float c_smooth, int nPerWave)
{
    const int lane = threadIdx.x & 63;
    const int gwid = (blockIdx.x * blockDim.x + threadIdx.x) >> 6;
    const int start = gwid * nPerWave;
    if (start >= N_NODES) return;
    const int end = min(N_NODES, start + nPerWave);

    const int l  = lane >> 4;
    const int wi = lane & 15;
    const int nl = 2 * l + 1;
    const int off = (l == 0 ? 0 : (l == 1 ? 16 : (l == 2 ? 64 : 144)));
    const int base = off + wi * nl;

    // lane m (= lane&31) computes h[m]; hoist W1 column into registers
    const int m = lane & 31;
    float w1c[10];
#pragma unroll
    for (int k = 0; k < 10; ++k) w1c[k] = W1[k * 32 + m];

    float acc[7];
#pragma unroll
    for (int k = 0; k < 7; ++k) acc[k] = 0.f;

    int curG = batch[start];
    int runCnt = 0;

    for (int i = start; i < end; ++i) {
        const int g = batch[i];   // uniform across wave
        if (g != curG) {
#pragma unroll
            for (int k = 0; k < 7; ++k)
                if (k < nl) { atomicAdd(&sums[curG * 256 + base + k], acc[k]); acc[k] = 0.f; }
            if (lane == 0) atomicAdd(&counts[curG], (float)runCnt);
            runCnt = 0; curG = g;
        }

        const float px = pos[3 * i], py = pos[3 * i + 1], pz = pos[3 * i + 2];
        const float Lsq = px * px + py * py + pz * pz;
        const float L = sqrtf(Lsq);

        // radial basis (smooth_finite, cutoff) -> h[m]  (sqrt(10)/W1-sqrt(10) cancel)
        const float tb = 1.1f * L;
        float hm = 0.f;
#pragma unroll
        for (int k = 0; k < 10; ++k) {
            const float a = tb - (float)k;
            const float b = (float)(k + 2) - tb;
            const float fa = (a > 0.f) ? expf(-1.f / a) : 0.f;
            const float fb = (b > 0.f) ? expf(-1.f / b) : 0.f;
            hm = fmaf(c_smooth * fa * fb, w1c[k], hm);
        }
        // normalized silu
        hm = silu_c * hm / (1.f + expf(-hm));

        // xw[j] = sum_m h[m] * T2[zm][j][m]
        const int zmi = xz[i] * 3 + mol[i];
        const float4* Tp = reinterpret_cast<const float4*>(T2 + (size_t)zmi * 2048 + lane * 32);
        float xwv = 0.f;
#pragma unroll
        for (int q = 0; q < 8; ++q) {
            const float4 tv = Tp[q];
            xwv = fmaf(__shfl(hm, 4 * q + 0), tv.x, xwv);
            xwv = fmaf(__shfl(hm, 4 * q + 1), tv.y, xwv);
            xwv = fmaf(__shfl(hm, 4 * q + 2), tv.z, xwv);
            xwv = fmaf(__shfl(hm, 4 * q + 3), tv.w, xwv);
        }

        // spherical harmonics (component normalization, each l * sqrt(2l+1))
        const float invL = 1.f / L;
        const float ux = px * invL, uy = py * invL, uz = pz * invL;
        const float s3 = 1.7320508075688772f, s5 = 2.2360679774997896f, s7 = 2.6457513110645907f;
        const float y2 = uy * uy, x2z2 = ux * ux + uz * uz;
        const float s20 = s3 * ux * uz;
        const float s21 = s3 * ux * uy;
        const float s22 = y2 - 0.5f * x2z2;
        const float s23 = s3 * uy * uz;
        const float s24 = 0.5f * s3 * (uz * uz - ux * ux);

        float shv[7];
#pragma unroll
        for (int k = 0; k < 7; ++k) shv[k] = 0.f;
        if (l == 0) {
            shv[0] = 1.f;
        } else if (l == 1) {
            shv[0] = s3 * ux; shv[1] = s3 * uy; shv[2] = s3 * uz;
        } else if (l == 2) {
            shv[0] = s5 * s20; shv[1] = s5 * s21; shv[2] = s5 * s22;
            shv[3] = s5 * s23; shv[4] = s5 * s24;
        } else {
            const float c56 = 0.9128709291752769f;  // sqrt(5/6)
            const float c38 = 0.6123724356957945f;  // sqrt(3/8)
            const float s30 = c56 * (s20 * uz + s24 * ux);
            const float s31 = s5 * s20 * uy;
            const float s32 = c38 * (4.f * y2 - x2z2) * ux;
            const float s33 = 0.5f * uy * (2.f * y2 - 3.f * x2z2);
            const float s34 = c38 * uz * (4.f * y2 - x2z2);
            const float s35 = s5 * s24 * uy;
            const float s36 = c56 * (s24 * uz - s20 * ux);
            shv[0] = s7 * s30; shv[1] = s7 * s31; shv[2] = s7 * s32;
            shv[3] = s7 * s33; shv[4] = s7 * s34; shv[5] = s7 * s35; shv[6] = s7 * s36;
        }

#pragma unroll
        for (int k = 0; k < 7; ++k)
            if (k < nl) acc[k] = fmaf(xwv, shv[k], acc[k]);
        ++runCnt;
    }

    // final flush
#pragma unroll
    for (int k = 0; k < 7; ++k)
        if (k < nl) atomicAdd(&sums[curG * 256 + base + k], acc[k]);
    if (lane == 0) atomicAdd(&counts[curG], (float)runCnt);
}

// ---------------------------------------------------------------------------
__global__ __launch_bounds__(256) void finalize(float* __restrict__ out,
                                                const float* __restrict__ counts)
{
    const int idx = blockIdx.x * blockDim.x + threadIdx.x;
    if (idx < G_SEG * 256)
        out[idx] = out[idx] / fmaxf(counts[idx >> 8], 1.f);
}

// ---------------------------------------------------------------------------
// e3nn normalize2mom constant for silu, replicated exactly (float64 trapezoid
// over linspace(-12,12,200001)).
static double silu_c_host()
{
    const int n = 200001;
    const double h = 24.0 / 200000.0;
    double sum = 0.0, prev = 0.0;
    for (int i = 0; i < n; ++i) {
        const double z = -12.0 + h * (double)i;
        const double pdf = exp(-0.5 * z * z) * 0.3989422804014327;  // 1/sqrt(2pi)
        const double s = z / (1.0 + exp(-z));
        const double f = s * s * pdf;
        if (i) sum += prev + f;
        prev = f;
    }
    sum *= 0.5 * h;
    return 1.0 / sqrt(sum);
}

extern "C" void kernel_launch(void* const* d_in, const int* in_sizes, int n_in,
                              void* d_out, int out_size, void* d_ws, size_t ws_size,
                              hipStream_t stream)
{
    const float* pos     = (const float*)d_in[0];
    const int*   xz      = (const int*)d_in[1];
    const int*   mol     = (const int*)d_in[2];
    const int*   batch   = (const int*)d_in[3];
    const float* emb_z   = (const float*)d_in[4];
    const float* emb_mol = (const float*)d_in[5];
    const float* W1      = (const float*)d_in[6];
    const float* W2      = (const float*)d_in[7];
    float* out = (float*)d_out;

    float* T2     = (float*)d_ws;            // 2,457,600 B
    float* counts = (float*)d_ws + T_ELEMS;  // + 2048 B

    static const float SILU_C_F  = (float)silu_c_host();
    const float c_smooth = (float)(1.14136 * exp(2.0));

    hipMemsetAsync(d_out, 0, (size_t)out_size * sizeof(float), stream);
    hipMemsetAsync(counts, 0, G_SEG * sizeof(float), stream);

    dim3 gA(300, 4);
    build_T<<<gA, 256, 0, stream>>>(emb_z, emb_mol, W2, T2);

    const int nPerWave = 16;                       // 4096 waves
    node_kernel<<<1024, 256, 0, stream>>>(pos, xz, mol, batch, W1, T2, out, counts,
                                          SILU_C_F, c_smooth, nPerWave);

    finalize<<<512, 256, 0, stream>>>(out, counts);
}

// Round 2
// 118.713 us; speedup vs baseline: 1.0681x; 1.0681x over previous
//
#include <hip/hip_runtime.h>
#include <math.h>

#define N_NODES 65536
#define G_SEG   512
#define T_ELEMS (300 * 2048)     // T2[zm][j][m]: 300 x 64 x 32 floats = 2.4 MB
#define NH      2048             // h-table intervals over L in [0,10]
#define H_ELEMS ((NH + 1) * 32)  // 2049 x 32 floats = 262 KB

// ---------------------------------------------------------------------------
// Kernel A: T2[zm][j][m] = (1/sqrt(2048)) * sum_u feat_zm[u] * W2[m][l*1024+u*16+wi]
// ---------------------------------------------------------------------------
__global__ __launch_bounds__(256) void build_T(
    const float* __restrict__ emb_z, const float* __restrict__ emb_mol,
    const float* __restrict__ W2, float* __restrict__ T2)
{
    __shared__ float feat[64];
    const int zm = blockIdx.x;
    const int l  = blockIdx.y;
    const int z  = zm / 3, mo = zm % 3;
    const int t  = threadIdx.x;
    if (t < 48)      feat[t] = emb_z[z * 48 + t];
    else if (t < 64) feat[t] = emb_mol[mo * 16 + (t - 48)];
    __syncthreads();

    const float scale = 0.02209708691207961f;  // 1/sqrt(2048)
    const int wi  = t & 15;
    const int mlo = t >> 4;
#pragma unroll
    for (int i = 0; i < 2; ++i) {
        const int m = mlo + 16 * i;
        const float* w2p = W2 + m * 4096 + l * 1024 + wi;
        float acc = 0.f;
#pragma unroll 8
        for (int u = 0; u < 64; ++u)
            acc = fmaf(feat[u], w2p[u * 16], acc);
        T2[zm * 2048 + (l * 16 + wi) * 32 + m] = acc * scale;
    }
}

// ---------------------------------------------------------------------------
// Kernel A2: h-table. Htab[e][m] = SILU_C * silu( sum_k basis_k(L_e) * W1[k][m] )
// L_e = e * 10/2048, e in [0, 2048]. Built in f64 (one-time, exact-ish).
// h(10) == 0 exactly (all basis vanish), so clamped lookups give 0 for L>=10.
// ---------------------------------------------------------------------------
__global__ __launch_bounds__(256) void build_H(
    const float* __restrict__ W1, float* __restrict__ Htab, double silu_c)
{
    const int tid = blockIdx.x * blockDim.x + threadIdx.x;
    if (tid >= H_ELEMS) return;
    const int e = tid >> 5, m = tid & 31;
    const double L = (double)e * (10.0 / 2048.0);
    const double c = 1.14136 * exp(2.0);
    double p = 0.0;
    for (int k = 0; k < 10; ++k) {
        const double a = 1.1 * L - (double)k;
        const double b = (double)(k + 2) - 1.1 * L;
        // exp(-1/a)*exp(-1/b) = exp(-(a+b)/(ab)) = exp(-2/(ab)) since a+b==2
        const double basis = (a > 0.0 && b > 0.0) ? c * exp(-2.0 / (a * b)) : 0.0;
        p += basis * (double)W1[k * 32 + m];
    }
    const double h = silu_c * p / (1.0 + exp(-p));
    Htab[e * 32 + m] = (float)h;
}

// ---------------------------------------------------------------------------
// Kernel B: per-node pipeline + register-accumulated segment sum.
// Lane j = l*16+wi owns xw[l][wi]; keeps (2l+1) accumulators, flushes with
// atomics only at (sorted) batch boundaries. Radial MLP = table lerp.
// ---------------------------------------------------------------------------
__global__ __launch_bounds__(256) void node_kernel(
    const float* __restrict__ pos, const int* __restrict__ xz,
    const int* __restrict__ mol, const int* __restrict__ batch,
    const float* __restrict__ Htab, const float* __restrict__ T2,
    float* __restrict__ sums, float* __restrict__ counts, int nPerWave)
{
    const int lane = threadIdx.x & 63;
    const int gwid = (blockIdx.x * blockDim.x + threadIdx.x) >> 6;
    const int start = gwid * nPerWave;
    if (start >= N_NODES) return;
    const int end = min(N_NODES, start + nPerWave);

    const int l  = lane >> 4;
    const int wi = lane & 15;
    const int nl = 2 * l + 1;
    const int off = (l == 0 ? 0 : (l == 1 ? 16 : (l == 2 ? 64 : 144)));
    const int base = off + wi * nl;
    const int m = lane & 31;

    float acc[7];
#pragma unroll
    for (int k = 0; k < 7; ++k) acc[k] = 0.f;

    int curG = batch[start];
    int runCnt = 0;

#pragma unroll 2
    for (int i = start; i < end; ++i) {
        const int g = batch[i];
        if (g != curG) {
#pragma unroll
            for (int k = 0; k < 7; ++k)
                if (k < nl) { atomicAdd(&sums[curG * 256 + base + k], acc[k]); acc[k] = 0.f; }
            if (lane == 0) atomicAdd(&counts[curG], (float)runCnt);
            runCnt = 0; curG = g;
        }

        const float px = pos[3 * i], py = pos[3 * i + 1], pz = pos[3 * i + 2];
        const float Lsq = px * px + py * py + pz * pz;
        const float rinv = __builtin_amdgcn_rsqf(Lsq);
        const float L = Lsq * rinv;

        // radial MLP via table lerp (lane m covers h[m], duplicated per half-wave)
        float t = L * 204.8f;
        int i0 = (int)t;
        i0 = min(i0, NH - 1);
        const float fr = fminf(t - (float)i0, 1.f);
        const float h0 = Htab[i0 * 32 + m];
        const float h1 = Htab[i0 * 32 + 32 + m];
        const float hm = fmaf(fr, h1 - h0, h0);

        // xw[j] = sum_m h[m] * T2[zm][j][m]
        const int zmi = xz[i] * 3 + mol[i];
        const float4* Tp = reinterpret_cast<const float4*>(T2 + (size_t)zmi * 2048 + lane * 32);
        float xwv = 0.f;
#pragma unroll
        for (int q = 0; q < 8; ++q) {
            const float4 tv = Tp[q];
            xwv = fmaf(__shfl(hm, 4 * q + 0), tv.x, xwv);
            xwv = fmaf(__shfl(hm, 4 * q + 1), tv.y, xwv);
            xwv = fmaf(__shfl(hm, 4 * q + 2), tv.z, xwv);
            xwv = fmaf(__shfl(hm, 4 * q + 3), tv.w, xwv);
        }

        // spherical harmonics (component normalization)
        const float ux = px * rinv, uy = py * rinv, uz = pz * rinv;
        const float s3 = 1.7320508075688772f, s5 = 2.2360679774997896f, s7 = 2.6457513110645907f;
        const float y2 = uy * uy, x2z2 = ux * ux + uz * uz;
        const float s20 = s3 * ux * uz;
        const float s21 = s3 * ux * uy;
        const float s22 = y2 - 0.5f * x2z2;
        const float s23 = s3 * uy * uz;
        const float s24 = 0.5f * s3 * (uz * uz - ux * ux);

        float shv[7];
#pragma unroll
        for (int k = 0; k < 7; ++k) shv[k] = 0.f;
        if (l == 0) {
            shv[0] = 1.f;
        } else if (l == 1) {
            shv[0] = s3 * ux; shv[1] = s3 * uy; shv[2] = s3 * uz;
        } else if (l == 2) {
            shv[0] = s5 * s20; shv[1] = s5 * s21; shv[2] = s5 * s22;
            shv[3] = s5 * s23; shv[4] = s5 * s24;
        } else {
            const float c56 = 0.9128709291752769f;  // sqrt(5/6)
            const float c38 = 0.6123724356957945f;  // sqrt(3/8)
            const float s30 = c56 * (s20 * uz + s24 * ux);
            const float s31 = s5 * s20 * uy;
            const float s32 = c38 * (4.f * y2 - x2z2) * ux;
            const float s33 = 0.5f * uy * (2.f * y2 - 3.f * x2z2);
            const float s34 = c38 * uz * (4.f * y2 - x2z2);
            const float s35 = s5 * s24 * uy;
            const float s36 = c56 * (s24 * uz - s20 * ux);
            shv[0] = s7 * s30; shv[1] = s7 * s31; shv[2] = s7 * s32;
            shv[3] = s7 * s33; shv[4] = s7 * s34; shv[5] = s7 * s35; shv[6] = s7 * s36;
        }

#pragma unroll
        for (int k = 0; k < 7; ++k)
            if (k < nl) acc[k] = fmaf(xwv, shv[k], acc[k]);
        ++runCnt;
    }

#pragma unroll
    for (int k = 0; k < 7; ++k)
        if (k < nl) atomicAdd(&sums[curG * 256 + base + k], acc[k]);
    if (lane == 0) atomicAdd(&counts[curG], (float)runCnt);
}

// ---------------------------------------------------------------------------
__global__ __launch_bounds__(256) void finalize(float* __restrict__ out,
                                                const float* __restrict__ counts)
{
    const int idx = blockIdx.x * blockDim.x + threadIdx.x;
    if (idx < G_SEG * 256)
        out[idx] = out[idx] / fmaxf(counts[idx >> 8], 1.f);
}

// ---------------------------------------------------------------------------
static double silu_c_host()
{
    const int n = 200001;
    const double h = 24.0 / 200000.0;
    double sum = 0.0, prev = 0.0;
    for (int i = 0; i < n; ++i) {
        const double z = -12.0 + h * (double)i;
        const double pdf = exp(-0.5 * z * z) * 0.3989422804014327;
        const double s = z / (1.0 + exp(-z));
        const double f = s * s * pdf;
        if (i) sum += prev + f;
        prev = f;
    }
    sum *= 0.5 * h;
    return 1.0 / sqrt(sum);
}

extern "C" void kernel_launch(void* const* d_in, const int* in_sizes, int n_in,
                              void* d_out, int out_size, void* d_ws, size_t ws_size,
                              hipStream_t stream)
{
    const float* pos     = (const float*)d_in[0];
    const int*   xz      = (const int*)d_in[1];
    const int*   mol     = (const int*)d_in[2];
    const int*   batch   = (const int*)d_in[3];
    const float* emb_z   = (const float*)d_in[4];
    const float* emb_mol = (const float*)d_in[5];
    const float* W1      = (const float*)d_in[6];
    const float* W2      = (const float*)d_in[7];
    float* out = (float*)d_out;

    float* T2     = (float*)d_ws;                     // 2.4 MB
    float* Htab   = (float*)d_ws + T_ELEMS;           // 262 KB
    float* counts = (float*)d_ws + T_ELEMS + H_ELEMS; // 2 KB

    static const double SILU_C_D = silu_c_host();

    hipMemsetAsync(d_out, 0, (size_t)out_size * sizeof(float), stream);
    hipMemsetAsync(counts, 0, G_SEG * sizeof(float), stream);

    dim3 gA(300, 4);
    build_T<<<gA, 256, 0, stream>>>(emb_z, emb_mol, W2, T2);
    build_H<<<(H_ELEMS + 255) / 256, 256, 0, stream>>>(W1, Htab, SILU_C_D);

    const int nPerWave = 8;                         // 8192 waves
    node_kernel<<<2048, 256, 0, stream>>>(pos, xz, mol, batch, Htab, T2, out, counts,
                                          nPerWave);

    finalize<<<512, 256, 0, stream>>>(out, counts);
}